// Round 10
// baseline (138.573 us; speedup 1.0000x reference)
//
#include <hip/hip_runtime.h>

// LRFGraphConv: out[v] = ((nbr_sum[v] - deg[v]*verts[v]) @ lrf[v]) @ W^T + maxN*b
//
// R10: ONE persistent kernel (256 blocks x 512 thr, 1 block/CU co-resident)
// with a software grid barrier. Phases:
//  A) scatter: edges assigned e==blockIdx (mod 256) (decorrelates the ring);
//     pairs bucketed into per-(range,block) sub-segments pairs[r][b][CAP=64].
//     Slot = LDS atomic-return. NO global atomics.
//  B) accum: block r owns range r (256 verts): cnt-guided gather of its
//     sub-segments, fp32 LDS accumulation, write nbrdeg + atomicMax(maxN).
//  C) projection: all blocks stride over V*32 float4 outputs.
// Barrier counters zeroed by a 16B hipMemsetAsync (proven ~free in R9 A/B).

#define NBLK  256
#define NTHR  512
#define RBITS 8
#define RSIZE 256      // vertices per range
#define CAP   64       // per-(range,block) sub-segment capacity (mean ~16)
#define CBITS 6

__device__ __forceinline__ void grid_barrier(unsigned* ctr, unsigned target) {
    __syncthreads();
    if (threadIdx.x == 0) {
        __threadfence();   // release: publish this block's writes (L2 wb)
        __hip_atomic_fetch_add(ctr, 1u, __ATOMIC_ACQ_REL, __HIP_MEMORY_SCOPE_AGENT);
        while (__hip_atomic_load(ctr, __ATOMIC_ACQUIRE, __HIP_MEMORY_SCOPE_AGENT) < target)
            __builtin_amdgcn_s_sleep(1);
    }
    __syncthreads();
}

__global__ __launch_bounds__(NTHR, 2)
void lrf_mega(const float* __restrict__ verts,
              const int*   __restrict__ edges,
              const float* __restrict__ lrf,
              const float4* __restrict__ W4,
              const float4* __restrict__ bias4,
              unsigned* __restrict__ ctr,      // [2] zeroed (we use ctr[0])
              int* __restrict__ gmax,          // zeroed
              unsigned* __restrict__ cnt,      // [NR*NBLK]
              unsigned* __restrict__ pairs,    // [NR][NBLK][CAP]
              float4* __restrict__ nbrdeg,     // [V]
              float4* __restrict__ out4,       // [V*32]
              int V, int E, int NR) {
    __shared__ unsigned curL[RSIZE];   // NR <= 256
    __shared__ unsigned cntL[NBLK];
    __shared__ float4   accL[RSIZE];
    __shared__ int      wmax[NTHR / 64];

    const int b = blockIdx.x;
    const int t = threadIdx.x;

    // ---------------- Phase A: scatter ----------------
    for (int i = t; i < NR; i += NTHR) curL[i] = 0u;
    __syncthreads();

    for (int j = t;; j += NTHR) {
        int e = b + (j << 8);            // e == b (mod 256): ring decorrelated
        if (e >= E) break;
        int2 ed = ((const int2*)edges)[e];
        int r = ed.x >> RBITS;           // center ed.x gets neighbor ed.y
        unsigned s = atomicAdd(&curL[r], 1u);
        if (s < CAP)
            pairs[((unsigned)((r << 8) | b) << CBITS) + s] =
                ((unsigned)ed.y << RBITS) | ((unsigned)ed.x & (RSIZE - 1));
        r = ed.y >> RBITS;               // center ed.y gets neighbor ed.x
        s = atomicAdd(&curL[r], 1u);
        if (s < CAP)
            pairs[((unsigned)((r << 8) | b) << CBITS) + s] =
                ((unsigned)ed.x << RBITS) | ((unsigned)ed.y & (RSIZE - 1));
    }
    __syncthreads();
    for (int r = t; r < NR; r += NTHR)
        cnt[(r << 8) | b] = min(curL[r], (unsigned)CAP);

    grid_barrier(ctr, NBLK);

    // ---------------- Phase B: accumulate range b ----------------
    if (b < NR) {
        int v0 = b << RBITS;
        int nv = min(RSIZE, V - v0);
        if (t < RSIZE) accL[t] = make_float4(0.f, 0.f, 0.f, 0.f);
        for (int i = t; i < NBLK; i += NTHR) cntL[i] = cnt[(b << 8) | i];
        __syncthreads();

        for (int s = t; s < NBLK * CAP; s += NTHR) {
            int blk = s >> CBITS;
            int j = s & (CAP - 1);
            if ((unsigned)j < cntL[blk]) {
                unsigned pk = pairs[((unsigned)((b << 8) | blk) << CBITS) + j];
                int nb = (int)(pk >> RBITS);
                int cl = (int)(pk & (RSIZE - 1));
                float* ap = (float*)&accL[cl];
                atomicAdd(ap + 0, verts[3 * nb + 0]);
                atomicAdd(ap + 1, verts[3 * nb + 1]);
                atomicAdd(ap + 2, verts[3 * nb + 2]);
                atomicAdd(ap + 3, 1.f);
            }
        }
        __syncthreads();

        int d = 0;
        if (t < nv) {
            float4 a4 = accL[t];
            nbrdeg[v0 + t] = a4;
            d = (int)a4.w;
        }
        #pragma unroll
        for (int off = 32; off > 0; off >>= 1)
            d = max(d, __shfl_down(d, off, 64));
        if ((t & 63) == 0) wmax[t >> 6] = d;
        __syncthreads();
        if (t == 0) {
            int m = wmax[0];
            #pragma unroll
            for (int w = 1; w < NTHR / 64; ++w) m = max(m, wmax[w]);
            atomicMax(gmax, m);
        }
    }

    grid_barrier(ctr, 2 * NBLK);

    // ---------------- Phase C: projection ----------------
    float mx = (float)*gmax;
    const int TOT = NBLK * NTHR;
    const int NITEM = V * 32;
    for (int item = b * NTHR + t; item < NITEM; item += TOT) {
        int v = item >> 5;
        int q = item & 31;

        float4 nd = nbrdeg[v];
        float s0 = nd.x - nd.w * verts[3 * v + 0];
        float s1 = nd.y - nd.w * verts[3 * v + 1];
        float s2 = nd.z - nd.w * verts[3 * v + 2];

        const float* L = lrf + (size_t)9 * v;
        float r0 = s0 * L[0] + s1 * L[3] + s2 * L[6];
        float r1 = s0 * L[1] + s1 * L[4] + s2 * L[7];
        float r2 = s0 * L[2] + s1 * L[5] + s2 * L[8];

        float4 w0 = W4[3 * q + 0];
        float4 w1 = W4[3 * q + 1];
        float4 w2 = W4[3 * q + 2];
        float4 bv = bias4[q];

        float4 o;
        o.x = r0 * w0.x + r1 * w0.y + r2 * w0.z + mx * bv.x;
        o.y = r0 * w0.w + r1 * w1.x + r2 * w1.y + mx * bv.y;
        o.z = r0 * w1.z + r1 * w1.w + r2 * w2.x + mx * bv.z;
        o.w = r0 * w2.y + r1 * w2.z + r2 * w2.w + mx * bv.w;
        out4[item] = o;
    }
}

extern "C" void kernel_launch(void* const* d_in, const int* in_sizes, int n_in,
                              void* d_out, int out_size, void* d_ws, size_t ws_size,
                              hipStream_t stream) {
    const float* verts = (const float*)d_in[0];
    const int*   edges = (const int*)d_in[1];
    const float* lrf   = (const float*)d_in[2];
    const float* W     = (const float*)d_in[3];
    const float* bias  = (const float*)d_in[4];

    int V = in_sizes[0] / 3;
    int E = in_sizes[1] / 2;
    int NR = (V + RSIZE - 1) >> RBITS;       // 196 ranges

    // ---- workspace layout ----
    // [ctr 2 u32][gmax int][pad to 16][cnt NR*NBLK u32][pairs NR*NBLK*CAP u32]
    // [nbrdeg V float4]
    char* ws = (char*)d_ws;
    unsigned* ctr  = (unsigned*)ws;
    int*      gmax = (int*)(ws + 8);
    size_t off = 16;
    unsigned* cnt   = (unsigned*)(ws + off); off += (size_t)NR * NBLK * 4;
    unsigned* pairs = (unsigned*)(ws + off); off += (size_t)NR * NBLK * CAP * 4;
    off = (off + 15) & ~(size_t)15;
    float4*   nbrdeg = (float4*)(ws + off);

    // zero barrier counters + gmax (capture-legal; measured ~free in R9 A/B)
    (void)hipMemsetAsync(d_ws, 0, 16, stream);

    lrf_mega<<<NBLK, NTHR, 0, stream>>>(verts, edges, lrf,
                                        (const float4*)W, (const float4*)bias,
                                        ctr, gmax, cnt, pairs, nbrdeg,
                                        (float4*)d_out, V, E, NR);
}

// Round 11
// 59.074 us; speedup vs baseline: 2.3458x; 2.3458x over previous
//
#include <hip/hip_runtime.h>

// LRFGraphConv: out[v] = ((nbr_sum[v] - deg[v]*verts[v]) @ lrf[v]) @ W^T + maxN*b
//
// R11: 3 dispatches, ZERO global atomics, ZERO pre-zeroing.
//  K1 scatter: block = 1024 edges. LDS bucket-sort its 2048 directed pairs by
//     center-range (RSIZE=256): LDS rank atomics + 256-wide scan, then flush
//     the block's private contiguous 8KB pairs region COALESCED. Write
//     cnt[r][b], off[r][b] (plain stores, fully overwritten every call).
//  K2 accum: block r stages cnt/off rows, prefix-scans 512 entries in LDS,
//     binary-search work assignment (100% lane util), fp32 LDS accumulation,
//     writes nbrdeg + rmax[r] (plain store).
//  K3 lrf_out: block-local max-reduce of rmax[NR], then rotate+project.

#define RBITS 8
#define RSIZE 256
#define STHR  512          // scatter threads (1 int4 = 2 edges each)
#define PPB   2048         // pairs per scatter block
#define NBMAX 512          // accum scan width (supports NB <= 512)
#define NRMAX 256

// ---------------- K1: block-local bucket sort + coalesced flush -------------
__global__ __launch_bounds__(512)
void scatter_kernel(const int* __restrict__ edges,
                    unsigned* __restrict__ cntg,   // [NR*NB]
                    unsigned* __restrict__ offg,   // [NR*NB]
                    unsigned* __restrict__ gpairs, // [NB*PPB]
                    int E, int NR, int NB) {
    __shared__ unsigned cnt[NRMAX];
    __shared__ unsigned sc[NRMAX];
    __shared__ unsigned stage[PPB];
    const int b = blockIdx.x, t = threadIdx.x;
    if (t < NRMAX) cnt[t] = 0u;
    __syncthreads();

    int i4 = b * STHR + t;
    int e0 = 2 * i4, e1 = e0 + 1;
    int rr[4]; unsigned pk[4]; unsigned rk[4]; int np = 0;
    if (e1 < E) {
        int4 e = ((const int4*)edges)[i4];
        rr[0] = e.x >> RBITS; pk[0] = ((unsigned)e.y << RBITS) | ((unsigned)e.x & (RSIZE - 1));
        rr[1] = e.y >> RBITS; pk[1] = ((unsigned)e.x << RBITS) | ((unsigned)e.y & (RSIZE - 1));
        rr[2] = e.z >> RBITS; pk[2] = ((unsigned)e.w << RBITS) | ((unsigned)e.z & (RSIZE - 1));
        rr[3] = e.w >> RBITS; pk[3] = ((unsigned)e.z << RBITS) | ((unsigned)e.w & (RSIZE - 1));
        np = 4;
    } else if (e0 < E) {
        int2 e = ((const int2*)edges)[e0];
        rr[0] = e.x >> RBITS; pk[0] = ((unsigned)e.y << RBITS) | ((unsigned)e.x & (RSIZE - 1));
        rr[1] = e.y >> RBITS; pk[1] = ((unsigned)e.x << RBITS) | ((unsigned)e.y & (RSIZE - 1));
        np = 2;
    }
    #pragma unroll
    for (int j = 0; j < 4; ++j)
        if (j < np) rk[j] = atomicAdd(&cnt[rr[j]], 1u);
    __syncthreads();

    // inclusive scan of cnt[0..255] -> sc (all threads hit barriers)
    if (t < NRMAX) sc[t] = cnt[t];
    __syncthreads();
    for (int d = 1; d < NRMAX; d <<= 1) {
        unsigned add = 0u;
        if (t < NRMAX && t >= d) add = sc[t - d];
        __syncthreads();
        if (t < NRMAX) sc[t] += add;
        __syncthreads();
    }

    #pragma unroll
    for (int j = 0; j < 4; ++j)
        if (j < np) stage[(sc[rr[j]] - cnt[rr[j]]) + rk[j]] = pk[j];
    __syncthreads();

    unsigned total = sc[NRMAX - 1];
    unsigned gbase = (unsigned)b * PPB;
    for (unsigned i = t; i < total; i += STHR)
        gpairs[gbase + i] = stage[i];
    if (t < NR) {
        cntg[t * NB + b] = cnt[t];
        offg[t * NB + b] = sc[t] - cnt[t];
    }
}

// ---------------- K2: per-range LDS accumulation ----------------------------
__global__ __launch_bounds__(512)
void accum_kernel(const float* __restrict__ verts,
                  const unsigned* __restrict__ cntg,
                  const unsigned* __restrict__ offg,
                  const unsigned* __restrict__ gpairs,
                  float4* __restrict__ nbrdeg,
                  float* __restrict__ rmax,
                  int V, int NB) {
    __shared__ float4 acc[RSIZE];
    __shared__ unsigned C[NBMAX], O[NBMAX], S[NBMAX];
    __shared__ float wmaxs[8];
    const int r = blockIdx.x, t = threadIdx.x;
    if (t < RSIZE) acc[t] = make_float4(0.f, 0.f, 0.f, 0.f);
    unsigned c = 0u;
    if (t < NB) { c = cntg[r * NB + t]; O[t] = offg[r * NB + t]; }
    C[t] = c; S[t] = c;
    __syncthreads();
    for (int d = 1; d < NBMAX; d <<= 1) {
        unsigned add = (t >= d) ? S[t - d] : 0u;
        __syncthreads();
        S[t] += add;
        __syncthreads();
    }
    unsigned T = S[NBMAX - 1];

    for (unsigned i = t; i < T; i += 512) {
        // smallest b with S[b] > i
        int lo = 0, hi = NBMAX - 1;
        while (lo < hi) { int mid = (lo + hi) >> 1; if (S[mid] > i) hi = mid; else lo = mid + 1; }
        unsigned local = i - (S[lo] - C[lo]);
        unsigned pk = gpairs[(unsigned)lo * PPB + O[lo] + local];
        int nb = (int)(pk >> RBITS);
        int cl = (int)(pk & (RSIZE - 1));
        float* ap = (float*)&acc[cl];
        atomicAdd(ap + 0, verts[3 * nb + 0]);
        atomicAdd(ap + 1, verts[3 * nb + 1]);
        atomicAdd(ap + 2, verts[3 * nb + 2]);
        atomicAdd(ap + 3, 1.f);
    }
    __syncthreads();

    int v0 = r << RBITS;
    int nv = min(RSIZE, V - v0);
    float d = 0.f;
    if (t < nv) { float4 a4 = acc[t]; nbrdeg[v0 + t] = a4; d = a4.w; }
    #pragma unroll
    for (int off = 32; off > 0; off >>= 1)
        d = fmaxf(d, __shfl_down(d, off, 64));
    if ((t & 63) == 0) wmaxs[t >> 6] = d;
    __syncthreads();
    if (t == 0) {
        float m = wmaxs[0];
        #pragma unroll
        for (int w = 1; w < 8; ++w) m = fmaxf(m, wmaxs[w]);
        rmax[r] = m;
    }
}

// ---------------- K3: projection --------------------------------------------
__global__ __launch_bounds__(256)
void lrf_out(const float* __restrict__ verts,
             const float* __restrict__ lrf,
             const float4* __restrict__ W4,     // W as float4[96]
             const float4* __restrict__ bias4,  // bias as float4[32]
             const float4* __restrict__ nbrdeg,
             const float* __restrict__ rmax,
             float4* __restrict__ out4,         // out as float4[V*32]
             int V, int NR) {
    __shared__ float ms[4];
    const int t = threadIdx.x;
    float m = (t < NR) ? rmax[t] : 0.f;
    #pragma unroll
    for (int off = 32; off > 0; off >>= 1)
        m = fmaxf(m, __shfl_down(m, off, 64));
    if ((t & 63) == 0) ms[t >> 6] = m;
    __syncthreads();
    float mx = fmaxf(fmaxf(ms[0], ms[1]), fmaxf(ms[2], ms[3]));

    int item = blockIdx.x * 256 + t;
    if (item >= V * 32) return;
    int v = item >> 5;
    int q = item & 31;

    float4 nd = nbrdeg[v];
    float s0 = nd.x - nd.w * verts[3 * v + 0];
    float s1 = nd.y - nd.w * verts[3 * v + 1];
    float s2 = nd.z - nd.w * verts[3 * v + 2];

    const float* L = lrf + (size_t)9 * v;   // lrf[v,j,k] row-major
    float r0 = s0 * L[0] + s1 * L[3] + s2 * L[6];
    float r1 = s0 * L[1] + s1 * L[4] + s2 * L[7];
    float r2 = s0 * L[2] + s1 * L[5] + s2 * L[8];

    float4 w0 = W4[3 * q + 0];
    float4 w1 = W4[3 * q + 1];
    float4 w2 = W4[3 * q + 2];
    float4 bv = bias4[q];

    float4 o;
    o.x = r0 * w0.x + r1 * w0.y + r2 * w0.z + mx * bv.x;
    o.y = r0 * w0.w + r1 * w1.x + r2 * w1.y + mx * bv.y;
    o.z = r0 * w1.z + r1 * w1.w + r2 * w2.x + mx * bv.z;
    o.w = r0 * w2.y + r1 * w2.z + r2 * w2.w + mx * bv.w;
    out4[item] = o;
}

extern "C" void kernel_launch(void* const* d_in, const int* in_sizes, int n_in,
                              void* d_out, int out_size, void* d_ws, size_t ws_size,
                              hipStream_t stream) {
    const float* verts = (const float*)d_in[0];
    const int*   edges = (const int*)d_in[1];
    const float* lrf   = (const float*)d_in[2];
    const float* W     = (const float*)d_in[3];
    const float* bias  = (const float*)d_in[4];

    int V = in_sizes[0] / 3;
    int E = in_sizes[1] / 2;
    int NR = (V + RSIZE - 1) >> RBITS;          // 196 ranges
    int Ni4 = (E + 1) / 2;                      // int4 granules
    int NB = (Ni4 + STHR - 1) / STHR;           // 391 scatter blocks (<=512)

    // ---- workspace layout (all fully rewritten every call) ----
    // [cntg NR*NB][offg NR*NB][rmax NR f32][pad][gpairs NB*PPB][nbrdeg V f4]
    char* ws = (char*)d_ws;
    size_t off = 0;
    unsigned* cntg = (unsigned*)(ws + off);  off += (size_t)NR * NB * 4;
    unsigned* offg = (unsigned*)(ws + off);  off += (size_t)NR * NB * 4;
    float*    rmax = (float*)(ws + off);     off += (size_t)NR * 4;
    off = (off + 15) & ~(size_t)15;
    unsigned* gpairs = (unsigned*)(ws + off); off += (size_t)NB * PPB * 4;
    off = (off + 15) & ~(size_t)15;
    float4*   nbrdeg = (float4*)(ws + off);

    scatter_kernel<<<NB, STHR, 0, stream>>>(edges, cntg, offg, gpairs, E, NR, NB);

    accum_kernel<<<NR, 512, 0, stream>>>(verts, cntg, offg, gpairs,
                                         nbrdeg, rmax, V, NB);

    int ob = (V * 32 + 255) / 256;
    lrf_out<<<ob, 256, 0, stream>>>(verts, lrf, (const float4*)W,
                                    (const float4*)bias, nbrdeg, rmax,
                                    (float4*)d_out, V, NR);
}